// Round 9
// baseline (300.178 us; speedup 1.0000x reference)
//
#include <hip/hip_runtime.h>
#include <hip/hip_fp16.h>

// Problem constants (hard-coded from reference: LEVELS, heads, dims)
// Dtype model: fp32 buffers, values on f16 grid -> f16 MFMA.
#define BS 2
#define NQ 21760
#define NV 21760
#define DIM 256
#define NH 8
#define DH 32
#define NL 4
#define NP 4

typedef __attribute__((ext_vector_type(8))) _Float16 f16x8;
typedef __attribute__((ext_vector_type(4))) float f32x4;

__device__ __forceinline__ unsigned short f2h(float f) {
    return __half_as_ushort(__float2half(f));   // v_cvt_f16_f32 (RNE)
}
__device__ __forceinline__ float h2f(unsigned short s) {
    return __half2float(__ushort_as_half(s));
}

// ---------------------------------------------------------------------------
// W prep: weights -> f16, pre-swizzled into MFMA fragment order (identical
// layout for A- and B-operand use). Tile (nb,kb) = 64 lanes x 8 f16 = 1 KB.
// Regions: [qo: Wo(16nb)|Wa(8nb)][v: Wv 16nb][out: Wout 16nb], 8 kb each.
// ---------------------------------------------------------------------------
__global__ __launch_bounds__(64) void k_wprep(
    const float* __restrict__ Wo, const float* __restrict__ Wa,
    const float* __restrict__ Wv, const float* __restrict__ Wout,
    unsigned short* __restrict__ wsw)
{
    const int tile = blockIdx.x;
    const int lane = threadIdx.x;
    const float* W; int N, nb, kb;
    if (tile < 192) { nb = tile >> 3; kb = tile & 7;
        if (nb < 16) { W = Wo; N = 256; } else { W = Wa; N = 128; nb -= 16; } }
    else if (tile < 320) { int tt = tile - 192; nb = tt >> 3; kb = tt & 7; W = Wv;   N = 256; }
    else               { int tt = tile - 320; nb = tt >> 3; kb = tt & 7; W = Wout; N = 256; }
    const int quad = lane >> 4, l15 = lane & 15;
    const int col = nb * 16 + l15;
    unsigned int pk[4];
#pragma unroll
    for (int jj = 0; jj < 4; jj++) {
        int k0 = kb * 32 + quad * 8 + jj * 2;
        pk[jj] = (unsigned int)f2h(W[(size_t)k0 * N + col])
               | ((unsigned int)f2h(W[(size_t)(k0 + 1) * N + col]) << 16);
    }
    *(uint4*)(wsw + (size_t)tile * 512 + lane * 8) = *(const uint4*)pk;
}

// ---------------------------------------------------------------------------
// LDS-free swapped-operand 32-row GEMM cores. In the swapped form each lane's
// DATA fragment is 8 CONSECUTIVE elements of one row -> load it straight from
// global (no LDS, no barriers, no stage/compute duty cycle -- r7/r8 k_proj
// was pure achieved-BW-bound: dur = hbm_bytes / ~2 TB/s, with HBM idle
// during compute). Per wave: 4 quads x 32B cover full 128B lines per row.
// A = weight fragments (M m-tiles from mt0, wsw L2-hot), reloaded per K-half.
// C layout: lane col (l15) = data row, C row (quad*4+r) = wcol.
// ---------------------------------------------------------------------------
template<int M>
__device__ __forceinline__ void gemm32_dir_f32(const float* __restrict__ src,
                                               const unsigned short* __restrict__ wswb,
                                               int mt0, f32x4 acc[][2], int lane)
{
    const int quad = lane >> 4, l15 = lane & 15;
#pragma unroll
    for (int kh = 0; kh < 2; kh++) {
        f16x8 aw[M][4];
#pragma unroll
        for (int m = 0; m < M; m++)
#pragma unroll
            for (int j = 0; j < 4; j++)
                aw[m][j] = *(const f16x8*)(wswb +
                    ((((mt0 + m) * 8 + kh * 4 + j) << 9) + (lane << 3)));
#pragma unroll
        for (int j = 0; j < 4; j++) {
            const int kb = kh * 4 + j;
            f16x8 dq[2];
#pragma unroll
            for (int n = 0; n < 2; n++) {
                const float* p = src + (size_t)(n * 16 + l15) * 256 + kb * 32 + quad * 8;
                float4 fa = *(const float4*)p;
                float4 fb = *(const float4*)(p + 4);
                f16x8 d;
                d[0] = (_Float16)fa.x; d[1] = (_Float16)fa.y;
                d[2] = (_Float16)fa.z; d[3] = (_Float16)fa.w;
                d[4] = (_Float16)fb.x; d[5] = (_Float16)fb.y;
                d[6] = (_Float16)fb.z; d[7] = (_Float16)fb.w;
                dq[n] = d;
            }
#pragma unroll
            for (int m = 0; m < M; m++)
#pragma unroll
                for (int n = 0; n < 2; n++)
                    acc[m][n] = __builtin_amdgcn_mfma_f32_16x16x32_f16(aw[m][j], dq[n], acc[m][n], 0, 0, 0);
        }
    }
}
template<int M>
__device__ __forceinline__ void gemm32_dir_h16(const unsigned short* __restrict__ src,
                                               const unsigned short* __restrict__ wswb,
                                               int mt0, f32x4 acc[][2], int lane)
{
    const int quad = lane >> 4, l15 = lane & 15;
#pragma unroll
    for (int kh = 0; kh < 2; kh++) {
        f16x8 aw[M][4];
#pragma unroll
        for (int m = 0; m < M; m++)
#pragma unroll
            for (int j = 0; j < 4; j++)
                aw[m][j] = *(const f16x8*)(wswb +
                    ((((mt0 + m) * 8 + kh * 4 + j) << 9) + (lane << 3)));
#pragma unroll
        for (int j = 0; j < 4; j++) {
            const int kb = kh * 4 + j;
            f16x8 dq[2];
#pragma unroll
            for (int n = 0; n < 2; n++)
                dq[n] = *(const f16x8*)(src + (size_t)(n * 16 + l15) * 256 + kb * 32 + quad * 8);
#pragma unroll
            for (int m = 0; m < M; m++)
#pragma unroll
                for (int n = 0; n < 2; n++)
                    acc[m][n] = __builtin_amdgcn_mfma_f32_16x16x32_f16(aw[m][j], dq[n], acc[m][n], 0, 0, 0);
        }
    }
}

// K1: fused projections, LDS-free. Blocks [0,1360): v = value@Wv+bv -> f16
// head-major v_hm. Blocks [1360,2720): q@{Wo|Wa}, ALL 24 m-tiles in 2 passes
// over the same 32 rows (pass 2 re-reads the block's 32KB -> L1/L2-hot, so
// query costs HBM once; r8 proved the volume cut: FETCH 68->46 MB).
__global__ __launch_bounds__(256) void k_proj(
    const float* __restrict__ value,
    const float* __restrict__ query,
    const float* __restrict__ refp,
    const unsigned short* __restrict__ wsw,
    const float* __restrict__ bv,
    const float* __restrict__ bo,
    const float* __restrict__ ba,
    unsigned short* __restrict__ v_hm,
    float* __restrict__ locs_ws,
    unsigned short* __restrict__ attw_b)
{
    const int t = threadIdx.x;
    const int w = t >> 6, lane = t & 63;
    const int quad = lane >> 4, l15 = lane & 15;

    if (blockIdx.x < 1360) {
        const int tile = blockIdx.x;
        const int bb = (tile >= 680);
        const int pix0 = tile * 32 - bb * NV;
        const float* src = value + (size_t)tile * 32 * 256;
        f32x4 acc[4][2];
#pragma unroll
        for (int m = 0; m < 4; m++)
#pragma unroll
            for (int n = 0; n < 2; n++) acc[m][n] = (f32x4){0.f, 0.f, 0.f, 0.f};
        gemm32_dir_f32<4>(src, wsw + 98304, w * 4, acc, lane);
#pragma unroll
        for (int m = 0; m < 4; m++) {
            const int col = w * 64 + m * 16 + quad * 4;
            const int h = col >> 5, ch = col & 31;
            const float4 bias = *(const float4*)(bv + col);
            unsigned short* __restrict__ vh =
                v_hm + ((size_t)(bb * NH + h) * NV + pix0) * DH + ch;
#pragma unroll
            for (int n = 0; n < 2; n++) {
                f32x4 a = acc[m][n];
                uint2 o;
                o.x = (unsigned int)f2h(a[0] + bias.x)
                    | ((unsigned int)f2h(a[1] + bias.y) << 16);
                o.y = (unsigned int)f2h(a[2] + bias.z)
                    | ((unsigned int)f2h(a[3] + bias.w) << 16);
                *(uint2*)(vh + (size_t)(n * 16 + l15) * DH) = o;
            }
        }
    } else {
        const int rt = blockIdx.x - 1360;
        const size_t r0 = (size_t)rt * 32;
        const float* src = query + r0 * 256;
#pragma unroll
        for (int pass = 0; pass < 2; pass++) {
            const int mt0 = pass * 12 + w * 3;
            f32x4 acc[3][2];
#pragma unroll
            for (int m = 0; m < 3; m++)
#pragma unroll
                for (int n = 0; n < 2; n++) acc[m][n] = (f32x4){0.f, 0.f, 0.f, 0.f};
            gemm32_dir_f32<3>(src, wsw, mt0, acc, lane);
#pragma unroll
            for (int m = 0; m < 3; m++) {
                const int mt = mt0 + m;
                if (mt < 16) {
                    // offs -> locs. wcols c0..c0+3: xy = bit0, l per lane.
                    const int c0 = mt * 16 + quad * 4;
                    const int l = (c0 >> 3) & 3;
                    const float rnorm = 1.f / (float)(128 >> l);
                    const float4 bias = *(const float4*)(bo + c0);
#pragma unroll
                    for (int n = 0; n < 2; n++) {
                        size_t row = r0 + n * 16 + l15;
                        float2 ref = *(const float2*)(refp + row * 8 + l * 2);
                        f32x4 a = acc[m][n];
                        float4 o;
                        o.x = ref.x + (a[0] + bias.x) * rnorm;
                        o.y = ref.y + (a[1] + bias.y) * rnorm;
                        o.z = ref.x + (a[2] + bias.z) * rnorm;
                        o.w = ref.y + (a[3] + bias.w) * rnorm;
                        *(float4*)(locs_ws + row * 256 + c0) = o;
                    }
                } else {
                    // attw: softmax over 16 lp = (quad x reg); h = mt-16.
                    const int c0 = (mt - 16) * 16 + quad * 4;
                    const float4 bias = *(const float4*)(ba + c0);
#pragma unroll
                    for (int n = 0; n < 2; n++) {
                        size_t row = r0 + n * 16 + l15;
                        f32x4 a = acc[m][n];
                        float v0 = a[0] + bias.x, v1 = a[1] + bias.y;
                        float v2 = a[2] + bias.z, v3 = a[3] + bias.w;
                        float mm = fmaxf(fmaxf(v0, v1), fmaxf(v2, v3));
                        mm = fmaxf(mm, __shfl_xor(mm, 16, 64));
                        mm = fmaxf(mm, __shfl_xor(mm, 32, 64));
                        float e0 = __expf(v0 - mm), e1 = __expf(v1 - mm);
                        float e2 = __expf(v2 - mm), e3 = __expf(v3 - mm);
                        float s = (e0 + e1) + (e2 + e3);
                        s += __shfl_xor(s, 16, 64);
                        s += __shfl_xor(s, 32, 64);
                        float rs = 1.f / s;
                        uint2 o;
                        o.x = (unsigned int)f2h(e0 * rs) | ((unsigned int)f2h(e1 * rs) << 16);
                        o.y = (unsigned int)f2h(e2 * rs) | ((unsigned int)f2h(e3 * rs) << 16);
                        *(uint2*)(attw_b + row * 128 + c0) = o;
                    }
                }
            }
        }
    }
}

// Accumulate 8 f16 channels (one uint4) with one weight via fma_mix.
__device__ __forceinline__ void acc8(float wf, uint4 d, float* ac)
{
    __half2 p0 = *(__half2*)&d.x;
    __half2 p1 = *(__half2*)&d.y;
    __half2 p2 = *(__half2*)&d.z;
    __half2 p3 = *(__half2*)&d.w;
    ac[0] = fmaf(wf, __half2float(__low2half(p0)),  ac[0]);
    ac[1] = fmaf(wf, __half2float(__high2half(p0)), ac[1]);
    ac[2] = fmaf(wf, __half2float(__low2half(p1)),  ac[2]);
    ac[3] = fmaf(wf, __half2float(__high2half(p1)), ac[3]);
    ac[4] = fmaf(wf, __half2float(__low2half(p2)),  ac[4]);
    ac[5] = fmaf(wf, __half2float(__high2half(p2)), ac[5]);
    ac[6] = fmaf(wf, __half2float(__low2half(p3)),  ac[6]);
    ac[7] = fmaf(wf, __half2float(__high2half(p3)), ac[7]);
}

// K2: fused tap-build + bilinear sampling, corner-paired gathers (r7 proven
// version: 68.7us, absmax 0.0156; r8's hfma2 doubled absmax for no gain).
__global__ __launch_bounds__(256) void k_sample(
    const unsigned short* __restrict__ v_hm,
    const float* __restrict__ locs_ws,
    const unsigned short* __restrict__ attw_b,
    unsigned short* __restrict__ msda_ws)
{
    __shared__ uint4 tap[16 * 2 * 33];   // [tp*2+dy][q pad33] = {wA,wB,off,-}
    const int t = threadIdx.x;
    const int bid = blockIdx.x;

    const int xcd  = bid & 7;
    const int slot = bid >> 3;                 // [0,1360)
    const int sub  = (slot >= 680) ? 1 : 0;
    const int chunk = slot - sub * 680;        // [0,680)
    const int pair = xcd * 2 + sub;            // [0,16)
    const int b = pair & 1;
    const int h = pair >> 1;
    const int q0 = chunk * 32;

    // ---- Phase 1: tp-fast -> 16 lanes read 128B contiguous locs per q.
#pragma unroll
    for (int i = 0; i < 2; i++) {
        const int item = t + i * 256;          // [0,512) = (q,tp)
        const int tp = item & 15;
        const int q  = item >> 4;
        const size_t row = (size_t)(b * NQ + q0 + q);
        float2 xy = *(const float2*)(locs_ws + row * 256 + h * 32 + tp * 2);
        float a   = h2f(attw_b[row * 128 + h * 16 + tp]);

        const int l = tp >> 2;
        const int Wl = 128 >> l;
        const float Wf = (float)Wl;
        const int start = (l == 0) ? 0 : (l == 1) ? 16384 : (l == 2) ? 20480 : 21504;
        float x = xy.x * Wf - 0.5f;
        float y = xy.y * Wf - 0.5f;
        float xf = floorf(x), yf = floorf(y);
        int x0 = (int)xf, y0 = (int)yf;
        float wx1 = x - xf, wx0 = 1.f - wx1;
        float wy1 = y - yf, wy0 = 1.f - wy1;
        const int base = min(max(x0, 0), Wl - 2);
        const int sh = x0 - base;              // 0 | -1 | 1 | other
        const float wxA = (sh == 0) ? wx0 : (sh == -1) ? wx1 : 0.f;
        const float wxB = (sh == 0) ? wx1 : (sh == 1)  ? wx0 : 0.f;
#pragma unroll
        for (int dy = 0; dy < 2; dy++) {
            int yi = y0 + dy;
            bool yv = (yi >= 0) && (yi < Wl);
            int yc = min(max(yi, 0), Wl - 1);
            float wY = yv ? a * (dy ? wy1 : wy0) : 0.f;
            uint4 rec;
            rec.x = __float_as_uint(wY * wxA);
            rec.y = __float_as_uint(wY * wxB);
            rec.z = (unsigned int)(start + yc * Wl + base) * 64u;  // f16 row=64B
            rec.w = 0u;
            tap[(tp * 2 + dy) * 33 + q] = rec;
        }
    }
    __syncthreads();

    // ---- Phase 2: lane owns (q, 8-ch group of one row of the pair).
    const int w4   = t >> 6;
    const int lane = t & 63;
    const int ql   = lane >> 3;
    const int g    = lane & 7;                 // 0..3 row A, 4..7 row B
    const int q    = w4 * 8 + ql;
    const bool selA = (g < 4);
    const unsigned int goff = (unsigned int)g * 16u;
    const char* __restrict__ vb =
        (const char*)(v_hm + (size_t)(b * NH + h) * NV * DH);

    float ac[8] = {0.f, 0.f, 0.f, 0.f, 0.f, 0.f, 0.f, 0.f};
#pragma unroll
    for (int it = 0; it < 32; it++) {
        uint4 rec = tap[it * 33 + q];
        float wf = __uint_as_float(selA ? rec.x : rec.y);
        uint4 d = *(const uint4*)(vb + (rec.z + goff));
        acc8(wf, d, ac);
    }
#pragma unroll
    for (int k = 0; k < 8; k++) ac[k] += __shfl_xor(ac[k], 4, 64);
    if (selA) {
        uint4 o;
        o.x = (unsigned int)f2h(ac[0]) | ((unsigned int)f2h(ac[1]) << 16);
        o.y = (unsigned int)f2h(ac[2]) | ((unsigned int)f2h(ac[3]) << 16);
        o.z = (unsigned int)f2h(ac[4]) | ((unsigned int)f2h(ac[5]) << 16);
        o.w = (unsigned int)f2h(ac[6]) | ((unsigned int)f2h(ac[7]) << 16);
        *(uint4*)(msda_ws + (size_t)(b * NQ + q0 + q) * DIM + h * DH + g * 8) = o;
    }
}

// K3: out = msda @ Wout + bout + query -> fp32. LDS-free direct f16 fragment
// loads (msda fragments ARE contiguous f16 -- zero conversion), 32-row tiles,
// wave w -> m-tiles 4w..4w+3, float4 epilogue with residual add.
__global__ __launch_bounds__(256) void k_out_mfma(
    const unsigned short* __restrict__ msda_ws,
    const unsigned short* __restrict__ wswo,
    const float* __restrict__ bout,
    const float* __restrict__ query,
    float* __restrict__ out)
{
    const int t = threadIdx.x;
    const int w = t >> 6, lane = t & 63;
    const int quad = lane >> 4, l15 = lane & 15;
    const size_t r0 = (size_t)blockIdx.x * 32;

    f32x4 acc[4][2];
#pragma unroll
    for (int m = 0; m < 4; m++)
#pragma unroll
        for (int n = 0; n < 2; n++) acc[m][n] = (f32x4){0.f, 0.f, 0.f, 0.f};
    gemm32_dir_h16<4>(msda_ws + r0 * 256, wswo, w * 4, acc, lane);

#pragma unroll
    for (int m = 0; m < 4; m++) {
        const int c0 = w * 64 + m * 16 + quad * 4;
        const float4 bias = *(const float4*)(bout + c0);
#pragma unroll
        for (int n = 0; n < 2; n++) {
            size_t row = r0 + n * 16 + l15;
            float4 q4 = *(const float4*)(query + row * 256 + c0);
            f32x4 a = acc[m][n];
            float4 o;
            o.x = a[0] + bias.x + q4.x;
            o.y = a[1] + bias.y + q4.y;
            o.z = a[2] + bias.z + q4.z;
            o.w = a[3] + bias.w + q4.w;
            *(float4*)(out + row * 256 + c0) = o;
        }
    }
}

extern "C" void kernel_launch(void* const* d_in, const int* in_sizes, int n_in,
                              void* d_out, int out_size, void* d_ws, size_t ws_size,
                              hipStream_t stream)
{
    const float* query = (const float*)d_in[0];
    const float* value = (const float*)d_in[1];
    const float* refp  = (const float*)d_in[2];
    // d_in[3] spatial_shapes, d_in[4] level_start_index : values hard-coded
    const float* Wv   = (const float*)d_in[5];
    const float* bv   = (const float*)d_in[6];
    const float* Wo   = (const float*)d_in[7];
    const float* bo   = (const float*)d_in[8];
    const float* Wa   = (const float*)d_in[9];
    const float* ba   = (const float*)d_in[10];
    const float* Wout = (const float*)d_in[11];
    const float* bout = (const float*)d_in[12];
    float* out = (float*)d_out;

    char* ws = (char*)d_ws;
    unsigned short* v_hm = (unsigned short*)ws;    ws += (size_t)BS * NH * NV * DH * 2; // 22.3 MB f16 head-major
    float* locs_ws = (float*)ws;                   ws += (size_t)BS * NQ * DIM * 4;     // 44.6 MB fp32
    unsigned short* attw_b = (unsigned short*)ws;  ws += (size_t)BS * NQ * 128 * 2;     // 11.1 MB f16
    unsigned short* msda_ws = (unsigned short*)ws; ws += (size_t)BS * NQ * DIM * 2;     // 22.3 MB f16
    unsigned short* wsw = (unsigned short*)ws;                                          // 448 KB

    k_wprep   <<<448, 64,  0, stream>>>(Wo, Wa, Wv, Wout, wsw);
    k_proj    <<<2720, 256, 0, stream>>>(value, query, refp, wsw, bv, bo, ba,
                                         v_hm, locs_ws, attw_b);
    k_sample  <<<10880, 256, 0, stream>>>(v_hm, locs_ws, attw_b, msda_ws);
    k_out_mfma<<<1360, 256, 0, stream>>>(msda_ws, wsw + 163840, bout, query, out);
}

// Round 10
// 267.377 us; speedup vs baseline: 1.1227x; 1.1227x over previous
//
#include <hip/hip_runtime.h>
#include <hip/hip_fp16.h>

// Problem constants (hard-coded from reference: LEVELS, heads, dims)
// Dtype model: fp32 buffers, values on f16 grid -> f16 MFMA.
#define BS 2
#define NQ 21760
#define NV 21760
#define DIM 256
#define NH 8
#define DH 32
#define NL 4
#define NP 4

typedef __attribute__((ext_vector_type(8))) _Float16 f16x8;
typedef __attribute__((ext_vector_type(4))) float f32x4;

__device__ __forceinline__ unsigned short f2h(float f) {
    return __half_as_ushort(__float2half(f));   // v_cvt_f16_f32 (RNE)
}
__device__ __forceinline__ float h2f(unsigned short s) {
    return __half2float(__ushort_as_half(s));
}

// ---------------------------------------------------------------------------
// W prep: weights -> f16, pre-swizzled into MFMA fragment order (identical
// layout for A- and B-operand use). Tile (nb,kb) = 64 lanes x 8 f16 = 1 KB.
// Regions: [qo: Wo(16nb)|Wa(8nb)][v: Wv 16nb][out: Wout 16nb], 8 kb each.
// ---------------------------------------------------------------------------
__global__ __launch_bounds__(64) void k_wprep(
    const float* __restrict__ Wo, const float* __restrict__ Wa,
    const float* __restrict__ Wv, const float* __restrict__ Wout,
    unsigned short* __restrict__ wsw)
{
    const int tile = blockIdx.x;
    const int lane = threadIdx.x;
    const float* W; int N, nb, kb;
    if (tile < 192) { nb = tile >> 3; kb = tile & 7;
        if (nb < 16) { W = Wo; N = 256; } else { W = Wa; N = 128; nb -= 16; } }
    else if (tile < 320) { int tt = tile - 192; nb = tt >> 3; kb = tt & 7; W = Wv;   N = 256; }
    else               { int tt = tile - 320; nb = tt >> 3; kb = tt & 7; W = Wout; N = 256; }
    const int quad = lane >> 4, l15 = lane & 15;
    const int col = nb * 16 + l15;
    unsigned int pk[4];
#pragma unroll
    for (int jj = 0; jj < 4; jj++) {
        int k0 = kb * 32 + quad * 8 + jj * 2;
        pk[jj] = (unsigned int)f2h(W[(size_t)k0 * N + col])
               | ((unsigned int)f2h(W[(size_t)(k0 + 1) * N + col]) << 16);
    }
    *(uint4*)(wsw + (size_t)tile * 512 + lane * 8) = *(const uint4*)pk;
}

// ---- Staging: 32 rows x 256 cols -> LDS f16 [32][264] (+8 pad). 256 thr ----
// LDS staging is the intra-block reuse mechanism: 4 waves consume one staged
// copy (r9's LDS-free variant re-read per wave -> 4x VMEM, 97us vs 70us).
__device__ __forceinline__ void stage32_f32(const float* __restrict__ src,
                                            unsigned short* __restrict__ As)
{
    const int t = threadIdx.x;
    const int colg = t & 63;
    const int row0 = t >> 6;
#pragma unroll
    for (int i = 0; i < 8; i++) {
        int row = row0 + i * 4;
        float4 f = ((const float4*)(src + (size_t)row * 256))[colg];
        uint2 p;
        p.x = (unsigned int)f2h(f.x) | ((unsigned int)f2h(f.y) << 16);
        p.y = (unsigned int)f2h(f.z) | ((unsigned int)f2h(f.w) << 16);
        *(uint2*)&As[row * 264 + colg * 4] = p;
    }
}
__device__ __forceinline__ void stage32_h16(const unsigned short* __restrict__ src,
                                            unsigned short* __restrict__ As)
{
    const int t = threadIdx.x;
    const int colg = t & 63;
    const int row0 = t >> 6;
#pragma unroll
    for (int i = 0; i < 8; i++) {
        int row = row0 + i * 4;
        uint2 u = ((const uint2*)(src + (size_t)row * 256))[colg];
        *(uint2*)&As[row * 264 + colg * 4] = u;
    }
}

// Swapped-operand 32-row GEMM core. A = weight fragments (M m-tiles of 16
// wcols starting at mt0), B = staged data rows (2 n-tiles of 16 rows).
// K processed in 2 halves with fragment reload (keeps VGPR ~52 -> 35% occ).
// C layout: lane col (l15) = data row, C row (quad*4+r) = wcol.
template<int M>
__device__ __forceinline__ void gemm32(const unsigned short* __restrict__ As,
                                       const unsigned short* __restrict__ wswb,
                                       int mt0, f32x4 acc[][2], int lane)
{
    const int quad = lane >> 4, l15 = lane & 15;
#pragma unroll
    for (int kh = 0; kh < 2; kh++) {
        f16x8 aw[M][4];
#pragma unroll
        for (int m = 0; m < M; m++)
#pragma unroll
            for (int j = 0; j < 4; j++)
                aw[m][j] = *(const f16x8*)(wswb +
                    ((((mt0 + m) * 8 + kh * 4 + j) << 9) + (lane << 3)));
#pragma unroll
        for (int j = 0; j < 4; j++) {
            const int kb = kh * 4 + j;
            f16x8 dq[2];
#pragma unroll
            for (int n = 0; n < 2; n++)
                dq[n] = *(const f16x8*)&As[(n * 16 + l15) * 264 + kb * 32 + quad * 8];
#pragma unroll
            for (int m = 0; m < M; m++)
#pragma unroll
                for (int n = 0; n < 2; n++)
                    acc[m][n] = __builtin_amdgcn_mfma_f32_16x16x32_f16(aw[m][j], dq[n], acc[m][n], 0, 0, 0);
        }
    }
}

// K1: fused projections = r7 staging structure + r8's traffic cut (q read
// ONCE: all 24 m-tiles in 2 passes over one staged tile) WITHOUT r8's
// register prefetch (VGPR 128 -> occupancy 17% -> BW 1.65 TB/s, net loss).
// Blocks [0,1360): v = value@Wv+bv -> f16 head-major v_hm, 32-row tile.
// Blocks [1360,2720): q@{Wo|Wa}, 2 passes of gemm32<3> per staged tile.
__global__ __launch_bounds__(256) void k_proj(
    const float* __restrict__ value,
    const float* __restrict__ query,
    const float* __restrict__ refp,
    const unsigned short* __restrict__ wsw,
    const float* __restrict__ bv,
    const float* __restrict__ bo,
    const float* __restrict__ ba,
    unsigned short* __restrict__ v_hm,
    float* __restrict__ locs_ws,
    unsigned short* __restrict__ attw_b)
{
    __shared__ unsigned short As[32 * 264];
    const int t = threadIdx.x;
    const int w = t >> 6, lane = t & 63;
    const int quad = lane >> 4, l15 = lane & 15;

    if (blockIdx.x < 1360) {
        const int tile = blockIdx.x;
        const int bb = (tile >= 680);
        const int pix0 = tile * 32 - bb * NV;
        stage32_f32(value + (size_t)tile * 32 * 256, As);
        __syncthreads();
        f32x4 acc[4][2];
#pragma unroll
        for (int m = 0; m < 4; m++)
#pragma unroll
            for (int n = 0; n < 2; n++) acc[m][n] = (f32x4){0.f, 0.f, 0.f, 0.f};
        gemm32<4>(As, wsw + 98304, w * 4, acc, lane);
#pragma unroll
        for (int m = 0; m < 4; m++) {
            const int col = w * 64 + m * 16 + quad * 4;
            const int h = col >> 5, ch = col & 31;
            const float4 bias = *(const float4*)(bv + col);
            unsigned short* __restrict__ vh =
                v_hm + ((size_t)(bb * NH + h) * NV + pix0) * DH + ch;
#pragma unroll
            for (int n = 0; n < 2; n++) {
                f32x4 a = acc[m][n];
                uint2 o;
                o.x = (unsigned int)f2h(a[0] + bias.x)
                    | ((unsigned int)f2h(a[1] + bias.y) << 16);
                o.y = (unsigned int)f2h(a[2] + bias.z)
                    | ((unsigned int)f2h(a[3] + bias.w) << 16);
                *(uint2*)(vh + (size_t)(n * 16 + l15) * DH) = o;
            }
        }
    } else {
        const int rt = blockIdx.x - 1360;
        const size_t r0 = (size_t)rt * 32;
        stage32_f32(query + r0 * 256, As);
        __syncthreads();
#pragma unroll
        for (int pass = 0; pass < 2; pass++) {
            const int mt0 = pass * 12 + w * 3;
            f32x4 acc[3][2];
#pragma unroll
            for (int m = 0; m < 3; m++)
#pragma unroll
                for (int n = 0; n < 2; n++) acc[m][n] = (f32x4){0.f, 0.f, 0.f, 0.f};
            gemm32<3>(As, wsw, mt0, acc, lane);
#pragma unroll
            for (int m = 0; m < 3; m++) {
                const int mt = mt0 + m;
                if (mt < 16) {
                    // offs -> locs. wcols c0..c0+3: xy = bit0, l per lane.
                    const int c0 = mt * 16 + quad * 4;
                    const int l = (c0 >> 3) & 3;
                    const float rnorm = 1.f / (float)(128 >> l);
                    const float4 bias = *(const float4*)(bo + c0);
#pragma unroll
                    for (int n = 0; n < 2; n++) {
                        size_t row = r0 + n * 16 + l15;
                        float2 ref = *(const float2*)(refp + row * 8 + l * 2);
                        f32x4 a = acc[m][n];
                        float4 o;
                        o.x = ref.x + (a[0] + bias.x) * rnorm;
                        o.y = ref.y + (a[1] + bias.y) * rnorm;
                        o.z = ref.x + (a[2] + bias.z) * rnorm;
                        o.w = ref.y + (a[3] + bias.w) * rnorm;
                        *(float4*)(locs_ws + row * 256 + c0) = o;
                    }
                } else {
                    // attw: softmax over 16 lp = (quad x reg); h = mt-16.
                    const int c0 = (mt - 16) * 16 + quad * 4;
                    const float4 bias = *(const float4*)(ba + c0);
#pragma unroll
                    for (int n = 0; n < 2; n++) {
                        size_t row = r0 + n * 16 + l15;
                        f32x4 a = acc[m][n];
                        float v0 = a[0] + bias.x, v1 = a[1] + bias.y;
                        float v2 = a[2] + bias.z, v3 = a[3] + bias.w;
                        float mm = fmaxf(fmaxf(v0, v1), fmaxf(v2, v3));
                        mm = fmaxf(mm, __shfl_xor(mm, 16, 64));
                        mm = fmaxf(mm, __shfl_xor(mm, 32, 64));
                        float e0 = __expf(v0 - mm), e1 = __expf(v1 - mm);
                        float e2 = __expf(v2 - mm), e3 = __expf(v3 - mm);
                        float s = (e0 + e1) + (e2 + e3);
                        s += __shfl_xor(s, 16, 64);
                        s += __shfl_xor(s, 32, 64);
                        float rs = 1.f / s;
                        uint2 o;
                        o.x = (unsigned int)f2h(e0 * rs) | ((unsigned int)f2h(e1 * rs) << 16);
                        o.y = (unsigned int)f2h(e2 * rs) | ((unsigned int)f2h(e3 * rs) << 16);
                        *(uint2*)(attw_b + row * 128 + c0) = o;
                    }
                }
            }
        }
    }
}

// Accumulate 8 f16 channels (one uint4) with one weight via fma_mix.
__device__ __forceinline__ void acc8(float wf, uint4 d, float* ac)
{
    __half2 p0 = *(__half2*)&d.x;
    __half2 p1 = *(__half2*)&d.y;
    __half2 p2 = *(__half2*)&d.z;
    __half2 p3 = *(__half2*)&d.w;
    ac[0] = fmaf(wf, __half2float(__low2half(p0)),  ac[0]);
    ac[1] = fmaf(wf, __half2float(__high2half(p0)), ac[1]);
    ac[2] = fmaf(wf, __half2float(__low2half(p1)),  ac[2]);
    ac[3] = fmaf(wf, __half2float(__high2half(p1)), ac[3]);
    ac[4] = fmaf(wf, __half2float(__low2half(p2)),  ac[4]);
    ac[5] = fmaf(wf, __half2float(__high2half(p2)), ac[5]);
    ac[6] = fmaf(wf, __half2float(__low2half(p3)),  ac[6]);
    ac[7] = fmaf(wf, __half2float(__high2half(p3)), ac[7]);
}

// K2: fused tap-build + bilinear sampling, corner-paired gathers (r7 proven
// version: 68.7us, absmax 0.0156).
__global__ __launch_bounds__(256) void k_sample(
    const unsigned short* __restrict__ v_hm,
    const float* __restrict__ locs_ws,
    const unsigned short* __restrict__ attw_b,
    unsigned short* __restrict__ msda_ws)
{
    __shared__ uint4 tap[16 * 2 * 33];   // [tp*2+dy][q pad33] = {wA,wB,off,-}
    const int t = threadIdx.x;
    const int bid = blockIdx.x;

    const int xcd  = bid & 7;
    const int slot = bid >> 3;                 // [0,1360)
    const int sub  = (slot >= 680) ? 1 : 0;
    const int chunk = slot - sub * 680;        // [0,680)
    const int pair = xcd * 2 + sub;            // [0,16)
    const int b = pair & 1;
    const int h = pair >> 1;
    const int q0 = chunk * 32;

    // ---- Phase 1: tp-fast -> 16 lanes read 128B contiguous locs per q.
#pragma unroll
    for (int i = 0; i < 2; i++) {
        const int item = t + i * 256;          // [0,512) = (q,tp)
        const int tp = item & 15;
        const int q  = item >> 4;
        const size_t row = (size_t)(b * NQ + q0 + q);
        float2 xy = *(const float2*)(locs_ws + row * 256 + h * 32 + tp * 2);
        float a   = h2f(attw_b[row * 128 + h * 16 + tp]);

        const int l = tp >> 2;
        const int Wl = 128 >> l;
        const float Wf = (float)Wl;
        const int start = (l == 0) ? 0 : (l == 1) ? 16384 : (l == 2) ? 20480 : 21504;
        float x = xy.x * Wf - 0.5f;
        float y = xy.y * Wf - 0.5f;
        float xf = floorf(x), yf = floorf(y);
        int x0 = (int)xf, y0 = (int)yf;
        float wx1 = x - xf, wx0 = 1.f - wx1;
        float wy1 = y - yf, wy0 = 1.f - wy1;
        const int base = min(max(x0, 0), Wl - 2);
        const int sh = x0 - base;              // 0 | -1 | 1 | other
        const float wxA = (sh == 0) ? wx0 : (sh == -1) ? wx1 : 0.f;
        const float wxB = (sh == 0) ? wx1 : (sh == 1)  ? wx0 : 0.f;
#pragma unroll
        for (int dy = 0; dy < 2; dy++) {
            int yi = y0 + dy;
            bool yv = (yi >= 0) && (yi < Wl);
            int yc = min(max(yi, 0), Wl - 1);
            float wY = yv ? a * (dy ? wy1 : wy0) : 0.f;
            uint4 rec;
            rec.x = __float_as_uint(wY * wxA);
            rec.y = __float_as_uint(wY * wxB);
            rec.z = (unsigned int)(start + yc * Wl + base) * 64u;  // f16 row=64B
            rec.w = 0u;
            tap[(tp * 2 + dy) * 33 + q] = rec;
        }
    }
    __syncthreads();

    // ---- Phase 2: lane owns (q, 8-ch group of one row of the pair).
    const int w4   = t >> 6;
    const int lane = t & 63;
    const int ql   = lane >> 3;
    const int g    = lane & 7;                 // 0..3 row A, 4..7 row B
    const int q    = w4 * 8 + ql;
    const bool selA = (g < 4);
    const unsigned int goff = (unsigned int)g * 16u;
    const char* __restrict__ vb =
        (const char*)(v_hm + (size_t)(b * NH + h) * NV * DH);

    float ac[8] = {0.f, 0.f, 0.f, 0.f, 0.f, 0.f, 0.f, 0.f};
#pragma unroll
    for (int it = 0; it < 32; it++) {
        uint4 rec = tap[it * 33 + q];
        float wf = __uint_as_float(selA ? rec.x : rec.y);
        uint4 d = *(const uint4*)(vb + (rec.z + goff));
        acc8(wf, d, ac);
    }
#pragma unroll
    for (int k = 0; k < 8; k++) ac[k] += __shfl_xor(ac[k], 4, 64);
    if (selA) {
        uint4 o;
        o.x = (unsigned int)f2h(ac[0]) | ((unsigned int)f2h(ac[1]) << 16);
        o.y = (unsigned int)f2h(ac[2]) | ((unsigned int)f2h(ac[3]) << 16);
        o.z = (unsigned int)f2h(ac[4]) | ((unsigned int)f2h(ac[5]) << 16);
        o.w = (unsigned int)f2h(ac[6]) | ((unsigned int)f2h(ac[7]) << 16);
        *(uint4*)(msda_ws + (size_t)(b * NQ + q0 + q) * DIM + h * DH + g * 8) = o;
    }
}

// K3: out = msda @ Wout + bout + query -> fp32. r7 LDS version (proven):
// 32-row tiles, 256 thr, wave w -> m-tiles 4w..4w+3, float4 epilogue.
__global__ __launch_bounds__(256) void k_out_mfma(
    const unsigned short* __restrict__ msda_ws,
    const unsigned short* __restrict__ wswo,
    const float* __restrict__ bout,
    const float* __restrict__ query,
    float* __restrict__ out)
{
    __shared__ unsigned short As[32 * 264];
    const int t = threadIdx.x;
    const int w = t >> 6, lane = t & 63;
    const int quad = lane >> 4, l15 = lane & 15;
    const size_t r0 = (size_t)blockIdx.x * 32;

    stage32_h16(msda_ws + r0 * 256, As);
    __syncthreads();

    f32x4 acc[4][2];
#pragma unroll
    for (int m = 0; m < 4; m++)
#pragma unroll
        for (int n = 0; n < 2; n++) acc[m][n] = (f32x4){0.f, 0.f, 0.f, 0.f};
    gemm32<4>(As, wswo, w * 4, acc, lane);

#pragma unroll
    for (int m = 0; m < 4; m++) {
        const int c0 = w * 64 + m * 16 + quad * 4;
        const float4 bias = *(const float4*)(bout + c0);
#pragma unroll
        for (int n = 0; n < 2; n++) {
            size_t row = r0 + n * 16 + l15;
            float4 q4 = *(const float4*)(query + row * 256 + c0);
            f32x4 a = acc[m][n];
            float4 o;
            o.x = a[0] + bias.x + q4.x;
            o.y = a[1] + bias.y + q4.y;
            o.z = a[2] + bias.z + q4.z;
            o.w = a[3] + bias.w + q4.w;
            *(float4*)(out + row * 256 + c0) = o;
        }
    }
}

extern "C" void kernel_launch(void* const* d_in, const int* in_sizes, int n_in,
                              void* d_out, int out_size, void* d_ws, size_t ws_size,
                              hipStream_t stream)
{
    const float* query = (const float*)d_in[0];
    const float* value = (const float*)d_in[1];
    const float* refp  = (const float*)d_in[2];
    // d_in[3] spatial_shapes, d_in[4] level_start_index : values hard-coded
    const float* Wv   = (const float*)d_in[5];
    const float* bv   = (const float*)d_in[6];
    const float* Wo   = (const float*)d_in[7];
    const float* bo   = (const float*)d_in[8];
    const float* Wa   = (const float*)d_in[9];
    const float* ba   = (const float*)d_in[10];
    const float* Wout = (const float*)d_in[11];
    const float* bout = (const float*)d_in[12];
    float* out = (float*)d_out;

    char* ws = (char*)d_ws;
    unsigned short* v_hm = (unsigned short*)ws;    ws += (size_t)BS * NH * NV * DH * 2; // 22.3 MB f16 head-major
    float* locs_ws = (float*)ws;                   ws += (size_t)BS * NQ * DIM * 4;     // 44.6 MB fp32
    unsigned short* attw_b = (unsigned short*)ws;  ws += (size_t)BS * NQ * 128 * 2;     // 11.1 MB f16
    unsigned short* msda_ws = (unsigned short*)ws; ws += (size_t)BS * NQ * DIM * 2;     // 22.3 MB f16
    unsigned short* wsw = (unsigned short*)ws;                                          // 448 KB

    k_wprep   <<<448, 64,  0, stream>>>(Wo, Wa, Wv, Wout, wsw);
    k_proj    <<<2720, 256, 0, stream>>>(value, query, refp, wsw, bv, bo, ba,
                                         v_hm, locs_ws, attw_b);
    k_sample  <<<10880, 256, 0, stream>>>(v_hm, locs_ws, attw_b, msda_ws);
    k_out_mfma<<<1360, 256, 0, stream>>>(msda_ws, wsw + 163840, bout, query, out);
}

// Round 11
// 262.876 us; speedup vs baseline: 1.1419x; 1.0171x over previous
//
#include <hip/hip_runtime.h>
#include <hip/hip_fp16.h>

// Problem constants (hard-coded from reference: LEVELS, heads, dims)
// Dtype model: fp32 buffers, values on f16 grid -> f16 MFMA.
#define BS 2
#define NQ 21760
#define NV 21760
#define DIM 256
#define NH 8
#define DH 32
#define NL 4
#define NP 4

typedef __attribute__((ext_vector_type(8))) _Float16 f16x8;
typedef __attribute__((ext_vector_type(4))) float f32x4;

__device__ __forceinline__ unsigned short f2h(float f) {
    return __half_as_ushort(__float2half(f));   // v_cvt_f16_f32 (RNE)
}
__device__ __forceinline__ float h2f(unsigned short s) {
    return __half2float(__ushort_as_half(s));
}

// ---------------------------------------------------------------------------
// W prep: weights -> f16, pre-swizzled into MFMA fragment order (identical
// layout for A- and B-operand use). Tile (nb,kb) = 64 lanes x 8 f16 = 1 KB.
// Regions: [qo: Wo(16nb)|Wa(8nb)][v: Wv 16nb][out: Wout 16nb], 8 kb each.
// ---------------------------------------------------------------------------
__global__ __launch_bounds__(64) void k_wprep(
    const float* __restrict__ Wo, const float* __restrict__ Wa,
    const float* __restrict__ Wv, const float* __restrict__ Wout,
    unsigned short* __restrict__ wsw)
{
    const int tile = blockIdx.x;
    const int lane = threadIdx.x;
    const float* W; int N, nb, kb;
    if (tile < 192) { nb = tile >> 3; kb = tile & 7;
        if (nb < 16) { W = Wo; N = 256; } else { W = Wa; N = 128; nb -= 16; } }
    else if (tile < 320) { int tt = tile - 192; nb = tt >> 3; kb = tt & 7; W = Wv;   N = 256; }
    else               { int tt = tile - 320; nb = tt >> 3; kb = tt & 7; W = Wout; N = 256; }
    const int quad = lane >> 4, l15 = lane & 15;
    const int col = nb * 16 + l15;
    unsigned int pk[4];
#pragma unroll
    for (int jj = 0; jj < 4; jj++) {
        int k0 = kb * 32 + quad * 8 + jj * 2;
        pk[jj] = (unsigned int)f2h(W[(size_t)k0 * N + col])
               | ((unsigned int)f2h(W[(size_t)(k0 + 1) * N + col]) << 16);
    }
    *(uint4*)(wsw + (size_t)tile * 512 + lane * 8) = *(const uint4*)pk;
}

// ---- Staging: 32 rows x 256 cols -> LDS f16 [32][264] (+8 pad). 256 thr ----
// LDS staging is the intra-block reuse mechanism: 4 waves consume one staged
// copy (r9's LDS-free variant re-read per wave -> 4x VMEM, 97us vs 70us).
__device__ __forceinline__ void stage32_f32(const float* __restrict__ src,
                                            unsigned short* __restrict__ As)
{
    const int t = threadIdx.x;
    const int colg = t & 63;
    const int row0 = t >> 6;
#pragma unroll
    for (int i = 0; i < 8; i++) {
        int row = row0 + i * 4;
        float4 f = ((const float4*)(src + (size_t)row * 256))[colg];
        uint2 p;
        p.x = (unsigned int)f2h(f.x) | ((unsigned int)f2h(f.y) << 16);
        p.y = (unsigned int)f2h(f.z) | ((unsigned int)f2h(f.w) << 16);
        *(uint2*)&As[row * 264 + colg * 4] = p;
    }
}
__device__ __forceinline__ void stage32_h16(const unsigned short* __restrict__ src,
                                            unsigned short* __restrict__ As)
{
    const int t = threadIdx.x;
    const int colg = t & 63;
    const int row0 = t >> 6;
#pragma unroll
    for (int i = 0; i < 8; i++) {
        int row = row0 + i * 4;
        uint2 u = ((const uint2*)(src + (size_t)row * 256))[colg];
        *(uint2*)&As[row * 264 + colg * 4] = u;
    }
}

// Swapped-operand 32-row GEMM core. A = weight fragments (M m-tiles of 16
// wcols starting at mt0), B = staged data rows (2 n-tiles of 16 rows).
// K processed in 2 halves with fragment reload (keeps VGPR ~52 -> high occ).
// C layout: lane col (l15) = data row, C row (quad*4+r) = wcol.
template<int M>
__device__ __forceinline__ void gemm32(const unsigned short* __restrict__ As,
                                       const unsigned short* __restrict__ wswb,
                                       int mt0, f32x4 acc[][2], int lane)
{
    const int quad = lane >> 4, l15 = lane & 15;
#pragma unroll
    for (int kh = 0; kh < 2; kh++) {
        f16x8 aw[M][4];
#pragma unroll
        for (int m = 0; m < M; m++)
#pragma unroll
            for (int j = 0; j < 4; j++)
                aw[m][j] = *(const f16x8*)(wswb +
                    ((((mt0 + m) * 8 + kh * 4 + j) << 9) + (lane << 3)));
#pragma unroll
        for (int j = 0; j < 4; j++) {
            const int kb = kh * 4 + j;
            f16x8 dq[2];
#pragma unroll
            for (int n = 0; n < 2; n++)
                dq[n] = *(const f16x8*)&As[(n * 16 + l15) * 264 + kb * 32 + quad * 8];
#pragma unroll
            for (int m = 0; m < M; m++)
#pragma unroll
                for (int n = 0; n < 2; n++)
                    acc[m][n] = __builtin_amdgcn_mfma_f32_16x16x32_f16(aw[m][j], dq[n], acc[m][n], 0, 0, 0);
        }
    }
}

// K1: fused projections. Blocks [0,1360): v = value@Wv+bv -> f16 head-major
//   v_hm, 32-row tile (r7/r10 proven).
// Blocks [1360,4080): q@{Wo|Wa}: r7's 2720-block parallelism (32-row x 12
//   m-tiles per block) + r10's traffic cut via XCD-PAIRING: the two col-half
//   blocks of the same rows share bid%8 (= XCD under round-robin dispatch,
//   ~8 apart in dispatch order), so the partner's 32KB query tile is an L2
//   hit -> query costs HBM once WITHOUT halving block count (r10 showed
//   traffic win == parallelism loss when merged into one block).
//   Mapping: qb = g + 8*(2*s + ch2), rt = 8*s + g.
__global__ __launch_bounds__(256) void k_proj(
    const float* __restrict__ value,
    const float* __restrict__ query,
    const float* __restrict__ refp,
    const unsigned short* __restrict__ wsw,
    const float* __restrict__ bv,
    const float* __restrict__ bo,
    const float* __restrict__ ba,
    unsigned short* __restrict__ v_hm,
    float* __restrict__ locs_ws,
    unsigned short* __restrict__ attw_b)
{
    __shared__ unsigned short As[32 * 264];
    const int t = threadIdx.x;
    const int w = t >> 6, lane = t & 63;
    const int quad = lane >> 4, l15 = lane & 15;

    if (blockIdx.x < 1360) {
        const int tile = blockIdx.x;
        const int bb = (tile >= 680);
        const int pix0 = tile * 32 - bb * NV;
        stage32_f32(value + (size_t)tile * 32 * 256, As);
        __syncthreads();
        f32x4 acc[4][2];
#pragma unroll
        for (int m = 0; m < 4; m++)
#pragma unroll
            for (int n = 0; n < 2; n++) acc[m][n] = (f32x4){0.f, 0.f, 0.f, 0.f};
        gemm32<4>(As, wsw + 98304, w * 4, acc, lane);
#pragma unroll
        for (int m = 0; m < 4; m++) {
            const int col = w * 64 + m * 16 + quad * 4;
            const int h = col >> 5, ch = col & 31;
            const float4 bias = *(const float4*)(bv + col);
            unsigned short* __restrict__ vh =
                v_hm + ((size_t)(bb * NH + h) * NV + pix0) * DH + ch;
#pragma unroll
            for (int n = 0; n < 2; n++) {
                f32x4 a = acc[m][n];
                uint2 o;
                o.x = (unsigned int)f2h(a[0] + bias.x)
                    | ((unsigned int)f2h(a[1] + bias.y) << 16);
                o.y = (unsigned int)f2h(a[2] + bias.z)
                    | ((unsigned int)f2h(a[3] + bias.w) << 16);
                *(uint2*)(vh + (size_t)(n * 16 + l15) * DH) = o;
            }
        }
    } else {
        const int qb = blockIdx.x - 1360;          // [0,2720)
        const int g  = qb & 7;                     // XCD slot
        const int mhi = qb >> 3;                   // [0,340)
        const int ch2 = mhi & 1;                   // col half
        const int s   = mhi >> 1;                  // [0,170)
        const int rt  = s * 8 + g;                 // row tile [0,1360)
        const size_t r0 = (size_t)rt * 32;
        stage32_f32(query + r0 * 256, As);
        __syncthreads();
        const int mt0 = ch2 * 12 + w * 3;
        f32x4 acc[3][2];
#pragma unroll
        for (int m = 0; m < 3; m++)
#pragma unroll
            for (int n = 0; n < 2; n++) acc[m][n] = (f32x4){0.f, 0.f, 0.f, 0.f};
        gemm32<3>(As, wsw, mt0, acc, lane);
#pragma unroll
        for (int m = 0; m < 3; m++) {
            const int mt = mt0 + m;
            if (mt < 16) {
                // offs -> locs. wcols c0..c0+3: xy = bit0, l fixed per lane.
                const int c0 = mt * 16 + quad * 4;
                const int l = (c0 >> 3) & 3;
                const float rnorm = 1.f / (float)(128 >> l);
                const float4 bias = *(const float4*)(bo + c0);
#pragma unroll
                for (int n = 0; n < 2; n++) {
                    size_t row = r0 + n * 16 + l15;
                    float2 ref = *(const float2*)(refp + row * 8 + l * 2);
                    f32x4 a = acc[m][n];
                    float4 o;
                    o.x = ref.x + (a[0] + bias.x) * rnorm;
                    o.y = ref.y + (a[1] + bias.y) * rnorm;
                    o.z = ref.x + (a[2] + bias.z) * rnorm;
                    o.w = ref.y + (a[3] + bias.w) * rnorm;
                    *(float4*)(locs_ws + row * 256 + c0) = o;
                }
            } else {
                // attw: softmax over 16 lp = (quad x reg); h = mt-16.
                const int c0 = (mt - 16) * 16 + quad * 4;
                const float4 bias = *(const float4*)(ba + c0);
#pragma unroll
                for (int n = 0; n < 2; n++) {
                    size_t row = r0 + n * 16 + l15;
                    f32x4 a = acc[m][n];
                    float v0 = a[0] + bias.x, v1 = a[1] + bias.y;
                    float v2 = a[2] + bias.z, v3 = a[3] + bias.w;
                    float mm = fmaxf(fmaxf(v0, v1), fmaxf(v2, v3));
                    mm = fmaxf(mm, __shfl_xor(mm, 16, 64));
                    mm = fmaxf(mm, __shfl_xor(mm, 32, 64));
                    float e0 = __expf(v0 - mm), e1 = __expf(v1 - mm);
                    float e2 = __expf(v2 - mm), e3 = __expf(v3 - mm);
                    float s2 = (e0 + e1) + (e2 + e3);
                    s2 += __shfl_xor(s2, 16, 64);
                    s2 += __shfl_xor(s2, 32, 64);
                    float rs = 1.f / s2;
                    uint2 o;
                    o.x = (unsigned int)f2h(e0 * rs) | ((unsigned int)f2h(e1 * rs) << 16);
                    o.y = (unsigned int)f2h(e2 * rs) | ((unsigned int)f2h(e3 * rs) << 16);
                    *(uint2*)(attw_b + row * 128 + c0) = o;
                }
            }
        }
    }
}

// Accumulate 8 f16 channels (one uint4) with one weight via fma_mix.
__device__ __forceinline__ void acc8(float wf, uint4 d, float* ac)
{
    __half2 p0 = *(__half2*)&d.x;
    __half2 p1 = *(__half2*)&d.y;
    __half2 p2 = *(__half2*)&d.z;
    __half2 p3 = *(__half2*)&d.w;
    ac[0] = fmaf(wf, __half2float(__low2half(p0)),  ac[0]);
    ac[1] = fmaf(wf, __half2float(__high2half(p0)), ac[1]);
    ac[2] = fmaf(wf, __half2float(__low2half(p1)),  ac[2]);
    ac[3] = fmaf(wf, __half2float(__high2half(p1)), ac[3]);
    ac[4] = fmaf(wf, __half2float(__low2half(p2)),  ac[4]);
    ac[5] = fmaf(wf, __half2float(__high2half(p2)), ac[5]);
    ac[6] = fmaf(wf, __half2float(__low2half(p3)),  ac[6]);
    ac[7] = fmaf(wf, __half2float(__high2half(p3)), ac[7]);
}

// K2: fused tap-build + bilinear sampling, corner-paired gathers (r7 proven
// version: 68.7us, absmax 0.0156).
__global__ __launch_bounds__(256) void k_sample(
    const unsigned short* __restrict__ v_hm,
    const float* __restrict__ locs_ws,
    const unsigned short* __restrict__ attw_b,
    unsigned short* __restrict__ msda_ws)
{
    __shared__ uint4 tap[16 * 2 * 33];   // [tp*2+dy][q pad33] = {wA,wB,off,-}
    const int t = threadIdx.x;
    const int bid = blockIdx.x;

    const int xcd  = bid & 7;
    const int slot = bid >> 3;                 // [0,1360)
    const int sub  = (slot >= 680) ? 1 : 0;
    const int chunk = slot - sub * 680;        // [0,680)
    const int pair = xcd * 2 + sub;            // [0,16)
    const int b = pair & 1;
    const int h = pair >> 1;
    const int q0 = chunk * 32;

    // ---- Phase 1: tp-fast -> 16 lanes read 128B contiguous locs per q.
#pragma unroll
    for (int i = 0; i < 2; i++) {
        const int item = t + i * 256;          // [0,512) = (q,tp)
        const int tp = item & 15;
        const int q  = item >> 4;
        const size_t row = (size_t)(b * NQ + q0 + q);
        float2 xy = *(const float2*)(locs_ws + row * 256 + h * 32 + tp * 2);
        float a   = h2f(attw_b[row * 128 + h * 16 + tp]);

        const int l = tp >> 2;
        const int Wl = 128 >> l;
        const float Wf = (float)Wl;
        const int start = (l == 0) ? 0 : (l == 1) ? 16384 : (l == 2) ? 20480 : 21504;
        float x = xy.x * Wf - 0.5f;
        float y = xy.y * Wf - 0.5f;
        float xf = floorf(x), yf = floorf(y);
        int x0 = (int)xf, y0 = (int)yf;
        float wx1 = x - xf, wx0 = 1.f - wx1;
        float wy1 = y - yf, wy0 = 1.f - wy1;
        const int base = min(max(x0, 0), Wl - 2);
        const int sh = x0 - base;              // 0 | -1 | 1 | other
        const float wxA = (sh == 0) ? wx0 : (sh == -1) ? wx1 : 0.f;
        const float wxB = (sh == 0) ? wx1 : (sh == 1)  ? wx0 : 0.f;
#pragma unroll
        for (int dy = 0; dy < 2; dy++) {
            int yi = y0 + dy;
            bool yv = (yi >= 0) && (yi < Wl);
            int yc = min(max(yi, 0), Wl - 1);
            float wY = yv ? a * (dy ? wy1 : wy0) : 0.f;
            uint4 rec;
            rec.x = __float_as_uint(wY * wxA);
            rec.y = __float_as_uint(wY * wxB);
            rec.z = (unsigned int)(start + yc * Wl + base) * 64u;  // f16 row=64B
            rec.w = 0u;
            tap[(tp * 2 + dy) * 33 + q] = rec;
        }
    }
    __syncthreads();

    // ---- Phase 2: lane owns (q, 8-ch group of one row of the pair).
    const int w4   = t >> 6;
    const int lane = t & 63;
    const int ql   = lane >> 3;
    const int g    = lane & 7;                 // 0..3 row A, 4..7 row B
    const int q    = w4 * 8 + ql;
    const bool selA = (g < 4);
    const unsigned int goff = (unsigned int)g * 16u;
    const char* __restrict__ vb =
        (const char*)(v_hm + (size_t)(b * NH + h) * NV * DH);

    float ac[8] = {0.f, 0.f, 0.f, 0.f, 0.f, 0.f, 0.f, 0.f};
#pragma unroll
    for (int it = 0; it < 32; it++) {
        uint4 rec = tap[it * 33 + q];
        float wf = __uint_as_float(selA ? rec.x : rec.y);
        uint4 d = *(const uint4*)(vb + (rec.z + goff));
        acc8(wf, d, ac);
    }
#pragma unroll
    for (int k = 0; k < 8; k++) ac[k] += __shfl_xor(ac[k], 4, 64);
    if (selA) {
        uint4 o;
        o.x = (unsigned int)f2h(ac[0]) | ((unsigned int)f2h(ac[1]) << 16);
        o.y = (unsigned int)f2h(ac[2]) | ((unsigned int)f2h(ac[3]) << 16);
        o.z = (unsigned int)f2h(ac[4]) | ((unsigned int)f2h(ac[5]) << 16);
        o.w = (unsigned int)f2h(ac[6]) | ((unsigned int)f2h(ac[7]) << 16);
        *(uint4*)(msda_ws + (size_t)(b * NQ + q0 + q) * DIM + h * DH + g * 8) = o;
    }
}

// K3: out = msda @ Wout + bout + query -> fp32. r7 LDS version (proven):
// 32-row tiles, 256 thr, wave w -> m-tiles 4w..4w+3, float4 epilogue.
__global__ __launch_bounds__(256) void k_out_mfma(
    const unsigned short* __restrict__ msda_ws,
    const unsigned short* __restrict__ wswo,
    const float* __restrict__ bout,
    const float* __restrict__ query,
    float* __restrict__ out)
{
    __shared__ unsigned short As[32 * 264];
    const int t = threadIdx.x;
    const int w = t >> 6, lane = t & 63;
    const int quad = lane >> 4, l15 = lane & 15;
    const size_t r0 = (size_t)blockIdx.x * 32;

    stage32_h16(msda_ws + r0 * 256, As);
    __syncthreads();

    f32x4 acc[4][2];
#pragma unroll
    for (int m = 0; m < 4; m++)
#pragma unroll
        for (int n = 0; n < 2; n++) acc[m][n] = (f32x4){0.f, 0.f, 0.f, 0.f};
    gemm32<4>(As, wswo, w * 4, acc, lane);

#pragma unroll
    for (int m = 0; m < 4; m++) {
        const int c0 = w * 64 + m * 16 + quad * 4;
        const float4 bias = *(const float4*)(bout + c0);
#pragma unroll
        for (int n = 0; n < 2; n++) {
            size_t row = r0 + n * 16 + l15;
            float4 q4 = *(const float4*)(query + row * 256 + c0);
            f32x4 a = acc[m][n];
            float4 o;
            o.x = a[0] + bias.x + q4.x;
            o.y = a[1] + bias.y + q4.y;
            o.z = a[2] + bias.z + q4.z;
            o.w = a[3] + bias.w + q4.w;
            *(float4*)(out + row * 256 + c0) = o;
        }
    }
}

extern "C" void kernel_launch(void* const* d_in, const int* in_sizes, int n_in,
                              void* d_out, int out_size, void* d_ws, size_t ws_size,
                              hipStream_t stream)
{
    const float* query = (const float*)d_in[0];
    const float* value = (const float*)d_in[1];
    const float* refp  = (const float*)d_in[2];
    // d_in[3] spatial_shapes, d_in[4] level_start_index : values hard-coded
    const float* Wv   = (const float*)d_in[5];
    const float* bv   = (const float*)d_in[6];
    const float* Wo   = (const float*)d_in[7];
    const float* bo   = (const float*)d_in[8];
    const float* Wa   = (const float*)d_in[9];
    const float* ba   = (const float*)d_in[10];
    const float* Wout = (const float*)d_in[11];
    const float* bout = (const float*)d_in[12];
    float* out = (float*)d_out;

    char* ws = (char*)d_ws;
    unsigned short* v_hm = (unsigned short*)ws;    ws += (size_t)BS * NH * NV * DH * 2; // 22.3 MB f16 head-major
    float* locs_ws = (float*)ws;                   ws += (size_t)BS * NQ * DIM * 4;     // 44.6 MB fp32
    unsigned short* attw_b = (unsigned short*)ws;  ws += (size_t)BS * NQ * 128 * 2;     // 11.1 MB f16
    unsigned short* msda_ws = (unsigned short*)ws; ws += (size_t)BS * NQ * DIM * 2;     // 22.3 MB f16
    unsigned short* wsw = (unsigned short*)ws;                                          // 448 KB

    k_wprep   <<<448, 64,  0, stream>>>(Wo, Wa, Wv, Wout, wsw);
    k_proj    <<<4080, 256, 0, stream>>>(value, query, refp, wsw, bv, bo, ba,
                                         v_hm, locs_ws, attw_b);
    k_sample  <<<10880, 256, 0, stream>>>(v_hm, locs_ws, attw_b, msda_ws);
    k_out_mfma<<<1360, 256, 0, stream>>>(msda_ws, wsw + 163840, bout, query, out);
}